// Round 6
// baseline (357.539 us; speedup 1.0000x reference)
//
#include <hip/hip_runtime.h>

typedef __attribute__((ext_vector_type(8))) short bf16x8;
typedef __attribute__((ext_vector_type(4))) float f32x4;

// ---------- helpers ----------
__device__ __forceinline__ float bflo(unsigned u) { return __uint_as_float(u << 16); }
__device__ __forceinline__ float bfhi(unsigned u) { return __uint_as_float(u & 0xFFFF0000u); }
__device__ __forceinline__ unsigned f2bf(float f) {
  unsigned u = __float_as_uint(f);
  u = (u + 0x7FFFu + ((u >> 16) & 1u)) >> 16;
  return u;  // low 16 bits valid
}

// ---------- fp32 -> bf16 bulk convert, two arrays in one launch ----------
__global__ void cvt2_kernel(const float* __restrict__ a, unsigned short* __restrict__ oa,
                            const float* __restrict__ b, unsigned short* __restrict__ ob,
                            int n8) {
  int i = blockIdx.x * 256 + threadIdx.x;
  if (i >= n8) return;
  const float* in = blockIdx.y ? b : a;
  unsigned short* out = blockIdx.y ? ob : oa;
  const float4* p = (const float4*)(in + (size_t)i * 8);
  float4 x = p[0], y = p[1];
  uint4 v;
  v.x = f2bf(x.x) | (f2bf(x.y) << 16);
  v.y = f2bf(x.z) | (f2bf(x.w) << 16);
  v.z = f2bf(y.x) | (f2bf(y.y) << 16);
  v.w = f2bf(y.z) | (f2bf(y.w) << 16);
  *(uint4*)(out + (size_t)i * 8) = v;
}

// ---------- composed relation weights (bf16 out, fp32 bias) ----------
__global__ void compose_w_kernel(const float* __restrict__ Wk, const float* __restrict__ bk,
                                 const float* __restrict__ Wv, const float* __restrict__ bv,
                                 const float* __restrict__ rel_att, const float* __restrict__ rel_msg,
                                 const float* __restrict__ rel_pri,
                                 unsigned short* __restrict__ Wkr, float* __restrict__ bkr,
                                 unsigned short* __restrict__ Wvr, float* __restrict__ bvr) {
  int e = blockIdx.x;   // relation
  int o = blockIdx.y;   // out index 0..127
  int z = blockIdx.z;   // 0 = att(k), 1 = msg(v)
  int c = threadIdx.x;  // in index 0..127
  int hd = o >> 4, j = o & 15;
  const int se[3] = {0, 1, 0};
  int s = se[e];
  const float* W = z ? Wv : Wk;
  const float* b = z ? bv : bk;
  const float* R = z ? rel_msg : rel_att;
  float scale = z ? 1.0f : (rel_pri[e * 8 + hd] * 0.25f);  // 1/sqrt(16)=0.25
  float acc = 0.0f, bacc = 0.0f;
#pragma unroll
  for (int i = 0; i < 16; ++i) {
    float r = R[((e * 8 + hd) * 16 + i) * 16 + j];
    acc += W[(s * 128 + hd * 16 + i) * 128 + c] * r;
    bacc += b[s * 128 + hd * 16 + i] * r;
  }
  unsigned short* Wo = z ? Wvr : Wkr;
  float* bo = z ? bvr : bkr;
  Wo[((size_t)e * 128 + o) * 128 + c] = (unsigned short)f2bf(acc * scale);
  if (c == 0) bo[e * 128 + o] = bacc * scale;
}

// ---------- fused MFMA projection GEMM: A staged once, loop over weight mats ----------
struct ProjFP {
  const float* A[2];  // h0, h1 fp32
  int M[2];
  int nj[2];                     // 5, 3
  const unsigned short* W[10];   // [type*5 + j]
  const float* b[10];
  unsigned short* out[10];
  int ostr[10];                  // row stride in shorts
};

__global__ __launch_bounds__(256) void proj_gemm_fused(ProjFP P) {
  __shared__ short As[128 * 128];
  __shared__ short Bs[128 * 128];
  int type = blockIdx.y;
  const float* __restrict__ A = P.A[type];
  int M = P.M[type];
  int nj = P.nj[type];
  int base = type * 5;
  int row0 = blockIdx.x * 128;
  if (row0 >= M) return;
  int t = threadIdx.x;
  bool full = (row0 + 128 <= M);
  // stage A (fp32 -> bf16) once
#pragma unroll
  for (int it = 0; it < 8; ++it) {
    int o = (it * 256 + t) * 8;
    int row = o >> 7, col = o & 127;
    int gr = row0 + row;
    uint4 av = make_uint4(0, 0, 0, 0);
    if (full || gr < M) {
      float4 x = *(const float4*)(A + (size_t)gr * 128 + col);
      float4 y = *(const float4*)(A + (size_t)gr * 128 + col + 4);
      av.x = f2bf(x.x) | (f2bf(x.y) << 16);
      av.y = f2bf(x.z) | (f2bf(x.w) << 16);
      av.z = f2bf(y.x) | (f2bf(y.y) << 16);
      av.w = f2bf(y.z) | (f2bf(y.w) << 16);
    }
    int sw = o ^ ((row & 7) << 3);
    *(uint4*)(&As[sw]) = av;
  }
  // stage B for job 0
  {
    const unsigned short* W0 = P.W[base];
#pragma unroll
    for (int it = 0; it < 8; ++it) {
      int o = (it * 256 + t) * 8;
      int row = o >> 7;
      int sw = o ^ ((row & 7) << 3);
      *(uint4*)(&Bs[sw]) = *(const uint4*)(W0 + o);
    }
  }
  __syncthreads();
  int wid = t >> 6, l = t & 63;
  int wr = wid >> 1, wc = wid & 1;  // 2x2 waves, 64x64 each
  int lr = l & 15, kb = l >> 4;
  for (int j = 0;; ++j) {
    f32x4 acc[4][4] = {};
#pragma unroll
    for (int ks = 0; ks < 4; ++ks) {
      bf16x8 af[4], bfr[4];
#pragma unroll
      for (int m = 0; m < 4; ++m) {
        int row = wr * 64 + m * 16 + lr;
        int h = (row * 128 + kb * 8 + ks * 32) ^ ((row & 7) << 3);
        af[m] = *(bf16x8*)(&As[h]);
      }
#pragma unroll
      for (int n = 0; n < 4; ++n) {
        int row = wc * 64 + n * 16 + lr;
        int h = (row * 128 + kb * 8 + ks * 32) ^ ((row & 7) << 3);
        bfr[n] = *(bf16x8*)(&Bs[h]);
      }
#pragma unroll
      for (int m = 0; m < 4; ++m)
#pragma unroll
        for (int n = 0; n < 4; ++n)
          acc[m][n] = __builtin_amdgcn_mfma_f32_16x16x32_bf16(af[m], bfr[n], acc[m][n], 0, 0, 0);
    }
    // epilogue for job j
    const float* bias = P.b[base + j];
    unsigned short* out = P.out[base + j];
    int ostr = P.ostr[base + j];
    int rb = row0 + wr * 64 + (l >> 4) * 4;
#pragma unroll
    for (int m = 0; m < 4; ++m)
#pragma unroll
      for (int jr = 0; jr < 4; ++jr) {
        int grow = rb + m * 16 + jr;
        if (grow < M) {
#pragma unroll
          for (int n = 0; n < 4; ++n) {
            int col = wc * 64 + n * 16 + lr;
            out[(size_t)grow * ostr + col] = (unsigned short)f2bf(acc[m][n][jr] + bias[col]);
          }
        }
      }
    if (j + 1 >= nj) break;
    __syncthreads();
    {
      const unsigned short* Wj = P.W[base + j + 1];
#pragma unroll
      for (int it = 0; it < 8; ++it) {
        int o = (it * 256 + t) * 8;
        int row = o >> 7;
        int sw = o ^ ((row & 7) << 3);
        *(uint4*)(&Bs[sw]) = *(const uint4*)(Wj + o);
      }
    }
    __syncthreads();
  }
}

// ---------- MFMA final GEMM: d_out = a*(Tb@Wa^T+ba) + (1-a)*h ----------
__global__ __launch_bounds__(256) void final_gemm_mfma(
    float* __restrict__ dout, const unsigned short* __restrict__ Tb0,
    const unsigned short* __restrict__ Tb1, const unsigned short* __restrict__ Wab,
    const float* __restrict__ ba, const float* __restrict__ h0, const float* __restrict__ h1,
    const float* __restrict__ skip, int N0, int N1) {
  __shared__ short As[128 * 128];
  __shared__ short Bs[128 * 128];
  int type = blockIdx.y;
  int M = type ? N1 : N0;
  const unsigned short* T = type ? Tb1 : Tb0;
  const unsigned short* W = Wab + (size_t)type * 16384;
  const float* bias = ba + type * 128;
  const float* h = type ? h1 : h0;
  float* O = dout + (type ? (size_t)N0 * 128 : 0);
  int row0 = blockIdx.x * 128;
  if (row0 >= M) return;
  int t = threadIdx.x;
  bool full = (row0 + 128 <= M);
#pragma unroll
  for (int it = 0; it < 8; ++it) {
    int o = (it * 256 + t) * 8;
    int row = o >> 7;
    int gr = row0 + row;
    uint4 av = make_uint4(0, 0, 0, 0);
    if (full || gr < M) av = *(const uint4*)(T + (size_t)gr * 128 + (o & 127));
    int sw = o ^ ((row & 7) << 3);
    *(uint4*)(&As[sw]) = av;
    uint4 wv = *(const uint4*)(W + o);
    *(uint4*)(&Bs[sw]) = wv;
  }
  __syncthreads();
  int wid = t >> 6, l = t & 63;
  int wr = wid >> 1, wc = wid & 1;
  int lr = l & 15, kb = l >> 4;
  f32x4 acc[4][4] = {};
#pragma unroll
  for (int ks = 0; ks < 4; ++ks) {
    bf16x8 af[4], bfr[4];
#pragma unroll
    for (int m = 0; m < 4; ++m) {
      int row = wr * 64 + m * 16 + lr;
      int h2 = (row * 128 + kb * 8 + ks * 32) ^ ((row & 7) << 3);
      af[m] = *(bf16x8*)(&As[h2]);
    }
#pragma unroll
    for (int n = 0; n < 4; ++n) {
      int row = wc * 64 + n * 16 + lr;
      int h2 = (row * 128 + kb * 8 + ks * 32) ^ ((row & 7) << 3);
      bfr[n] = *(bf16x8*)(&Bs[h2]);
    }
#pragma unroll
    for (int m = 0; m < 4; ++m)
#pragma unroll
      for (int n = 0; n < 4; ++n)
        acc[m][n] = __builtin_amdgcn_mfma_f32_16x16x32_bf16(af[m], bfr[n], acc[m][n], 0, 0, 0);
  }
  float alpha = 1.0f / (1.0f + __expf(-skip[type]));
  float beta = 1.0f - alpha;
  int rb = row0 + wr * 64 + (l >> 4) * 4;
#pragma unroll
  for (int m = 0; m < 4; ++m)
#pragma unroll
    for (int jr = 0; jr < 4; ++jr) {
      int grow = rb + m * 16 + jr;
      if (grow < M) {
#pragma unroll
        for (int n = 0; n < 4; ++n) {
          int col = wc * 64 + n * 16 + lr;
          float vout = alpha * (acc[m][n][jr] + bias[col]) + beta * h[(size_t)grow * 128 + col];
          O[(size_t)grow * 128 + col] = vout;
        }
      }
    }
}

// ---------- CSR build (batched over 3 relations via gridDim.y) ----------
__global__ void hist3_kernel(const int* __restrict__ d0, const int* __restrict__ d1,
                             const int* __restrict__ d2, int* __restrict__ cnt, int maxN, int E) {
  int r = blockIdx.y;
  int i = blockIdx.x * 256 + threadIdx.x;
  const int* dst = r == 0 ? d0 : (r == 1 ? d1 : d2);
  if (i < E) atomicAdd(&cnt[(size_t)r * maxN + dst[i]], 1);
}

__global__ void scan1_kernel(const int* __restrict__ cnt, int* __restrict__ rp0,
                             int* __restrict__ rp1, int* __restrict__ rp2,
                             int* __restrict__ bsum, int maxN, int n0, int n1, int n2) {
  __shared__ int sd[256];
  int r = blockIdx.y;
  int n = r == 0 ? n0 : (r == 1 ? n1 : n2);
  int* rp = r == 0 ? rp0 : (r == 1 ? rp1 : rp2);
  const int* c = cnt + (size_t)r * maxN;
  int t = threadIdx.x;
  int base = blockIdx.x * 1024 + t * 4;
  int x[4];
#pragma unroll
  for (int j = 0; j < 4; ++j) x[j] = (base + j < n) ? c[base + j] : 0;
  int tsum = x[0] + x[1] + x[2] + x[3];
  sd[t] = tsum;
  __syncthreads();
  for (int off = 1; off < 256; off <<= 1) {
    int v = (t >= off) ? sd[t - off] : 0;
    __syncthreads();
    sd[t] += v;
    __syncthreads();
  }
  int run = sd[t] - tsum;  // exclusive
#pragma unroll
  for (int j = 0; j < 4; ++j) {
    if (base + j < n) rp[base + j] = run;
    run += x[j];
  }
  if (t == 255) bsum[r * 256 + blockIdx.x] = sd[255];
}

// fused scan2+scan3: each block redundantly scans the <=256-entry block sums in LDS
__global__ void scan23_kernel(int* __restrict__ rp0, int* __restrict__ rp1, int* __restrict__ rp2,
                              const int* __restrict__ bsum, int nb, int n0, int n1, int n2,
                              int total) {
  __shared__ int sd[256];
  int r = blockIdx.y;
  int n = r == 0 ? n0 : (r == 1 ? n1 : n2);
  int* rp = r == 0 ? rp0 : (r == 1 ? rp1 : rp2);
  int t = threadIdx.x;
  int v = (t < nb) ? bsum[r * 256 + t] : 0;
  sd[t] = v;
  __syncthreads();
  for (int off = 1; off < 256; off <<= 1) {
    int u = (t >= off) ? sd[t - off] : 0;
    __syncthreads();
    sd[t] += u;
    __syncthreads();
  }
  int excl = sd[t] - v;
  __syncthreads();
  sd[t] = excl;
  __syncthreads();
  int i = blockIdx.x * 256 + t;
  if (i < n) rp[i] += sd[i >> 10];
  if (blockIdx.x == 0 && t == 0) rp[n] = total;
}

// scatter: slot -> (src, dst) pairs
__global__ void scatter3_kernel(const int* __restrict__ s0, const int* __restrict__ d0,
                                const int* __restrict__ s1, const int* __restrict__ d1,
                                const int* __restrict__ s2, const int* __restrict__ d2,
                                const int* __restrict__ rp0, const int* __restrict__ rp1,
                                const int* __restrict__ rp2, int* __restrict__ cur, int maxN,
                                int2* __restrict__ sd0, int2* __restrict__ sd1,
                                int2* __restrict__ sd2, int E) {
  int r = blockIdx.y;
  int i = blockIdx.x * 256 + threadIdx.x;
  if (i >= E) return;
  const int* src = r == 0 ? s0 : (r == 1 ? s1 : s2);
  const int* dst = r == 0 ? d0 : (r == 1 ? d1 : d2);
  const int* rp = r == 0 ? rp0 : (r == 1 ? rp1 : rp2);
  int2* sd = r == 0 ? sd0 : (r == 1 ? sd1 : sd2);
  int d = dst[i];
  int pos = rp[d] + atomicAdd(&cur[(size_t)r * maxN + d], 1);
  sd[pos] = make_int2(src[i], d);
}

// ---------- pass 1: edge-slot-parallel scores ----------
// lane = (slot g = t>>3, head h = t&7); each lane owns the full 16-elem head dot.
struct ScP {
  const int2* sd[3];
  const unsigned* kv[3];
  const unsigned* qb[3];      // q table of the relation's dst type
  unsigned short* eb[3];      // e[slot*8+h] bf16
  int E;
};

__global__ __launch_bounds__(256) void score_kernel(ScP P) {
  int r = blockIdx.y;
  const int2* __restrict__ sd = P.sd[r];
  const unsigned* __restrict__ kv = P.kv[r];
  const unsigned* __restrict__ qb = P.qb[r];
  unsigned short* __restrict__ eb = P.eb[r];
  int t = threadIdx.x;
  int p = blockIdx.x * 32 + (t >> 3);
  if (p >= P.E) return;
  int h = t & 7;
  int2 e2 = sd[p];
  const uint4* kr = (const uint4*)((const char*)kv + ((size_t)(unsigned)e2.x << 9) + h * 32);
  const uint4* qr = (const uint4*)((const char*)qb + ((size_t)(unsigned)e2.y << 8) + h * 32);
  uint4 k1 = kr[0], k2 = kr[1];
  uint4 q1 = qr[0], q2 = qr[1];
  float sc = 0.f;
#pragma unroll
  for (int c = 0; c < 4; ++c) {
    unsigned ku = ((const unsigned*)&k1)[c], qu = ((const unsigned*)&q1)[c];
    sc = fmaf(bflo(ku), bflo(qu), sc);
    sc = fmaf(bfhi(ku), bfhi(qu), sc);
  }
#pragma unroll
  for (int c = 0; c < 4; ++c) {
    unsigned ku = ((const unsigned*)&k2)[c], qu = ((const unsigned*)&q2)[c];
    sc = fmaf(bflo(ku), bflo(qu), sc);
    sc = fmaf(bfhi(ku), bfhi(qu), sc);
  }
  eb[(size_t)p * 8 + h] = (unsigned short)f2bf(__expf(sc));
}

// ---------- pass 2: light CSR aggregation (sum e*v and e, scale once) ----------
struct AgP {
  const int2 *sd0, *sd1, *sd2;
  const unsigned short *eb0, *eb1, *eb2;
  const unsigned *kv0, *kv1, *kv2;
  const int *rp0, *rp1, *rp2;
  unsigned *Tb0, *Tb1;
  int N0, N1;
};

__device__ __forceinline__ void agg_rel(const int2* __restrict__ sd,
                                        const unsigned short* __restrict__ eb,
                                        const unsigned* __restrict__ kv,
                                        const int* __restrict__ rp, int node, int l,
                                        float& r0, float& r1) {
  int beg = __builtin_amdgcn_readfirstlane(rp[node]);
  int end = __builtin_amdgcn_readfirstlane(rp[node + 1]);
  if (end <= beg) return;
  int h = l >> 3;
  const char* kvl = (const char*)kv + 256 + l * 4;  // v half, lane's uint
  const int* sdx = (const int*)sd;                  // stride-2 view for .x
  float a0 = 0.f, a1 = 0.f, den = 0.f;
  for (int p = beg; p < end; p += 4) {
    int idx = p + (l & 3);
    idx = idx < end ? idx : end - 1;
    int sv = sdx[(size_t)idx * 2];
#pragma unroll
    for (int j = 0; j < 4; ++j) {
      int pj = p + j;
      bool valid = pj < end;            // wave-uniform
      int pj2 = valid ? pj : end - 1;
      int s = __builtin_amdgcn_readlane(sv, j);
      float e = __uint_as_float((unsigned)eb[(size_t)pj2 * 8 + h] << 16);
      if (j && !valid) e = 0.f;
      unsigned v = *(const unsigned*)(kvl + ((size_t)(unsigned)s << 9));
      den += e;
      a0 = fmaf(e, bflo(v), a0);
      a1 = fmaf(e, bfhi(v), a1);
    }
  }
  float inv = 1.0f / den;
  r0 = fmaf(a0, inv, r0);
  r1 = fmaf(a1, inv, r1);
}

__global__ __launch_bounds__(256) void agg2_kernel(AgP P) {
  int gw = (blockIdx.x * 256 + threadIdx.x) >> 6;
  int l = threadIdx.x & 63;
  if (gw < P.N0) {
    float r0 = 0.f, r1 = 0.f;
    agg_rel(P.sd1, P.eb1, P.kv1, P.rp1, gw, l, r0, r1);
    agg_rel(P.sd2, P.eb2, P.kv2, P.rp2, gw, l, r0, r1);
    P.Tb0[(size_t)gw * 64 + l] = f2bf(r0 * 0.5f) | (f2bf(r1 * 0.5f) << 16);
  } else if (gw < P.N0 + P.N1) {
    int n = gw - P.N0;
    float r0 = 0.f, r1 = 0.f;
    agg_rel(P.sd0, P.eb0, P.kv0, P.rp0, n, l, r0, r1);
    P.Tb1[(size_t)n * 64 + l] = f2bf(r0) | (f2bf(r1) << 16);
  }
}

// ---------- host ----------
extern "C" void kernel_launch(void* const* d_in, const int* in_sizes, int n_in,
                              void* d_out, int out_size, void* d_ws, size_t ws_size,
                              hipStream_t stream) {
  const float* h0 = (const float*)d_in[0];
  const float* h1 = (const float*)d_in[1];
  const int* srcs[3] = {(const int*)d_in[2], (const int*)d_in[4], (const int*)d_in[6]};
  const int* dsts[3] = {(const int*)d_in[3], (const int*)d_in[5], (const int*)d_in[7]};
  const float* Wk = (const float*)d_in[8];
  const float* bk = (const float*)d_in[9];
  const float* Wq = (const float*)d_in[10];
  const float* bq = (const float*)d_in[11];
  const float* Wv = (const float*)d_in[12];
  const float* bv = (const float*)d_in[13];
  const float* Wa = (const float*)d_in[14];
  const float* ba = (const float*)d_in[15];
  const float* rel_att = (const float*)d_in[16];
  const float* rel_msg = (const float*)d_in[17];
  const float* rel_pri = (const float*)d_in[18];
  const float* skip = (const float*)d_in[19];

  int N0 = in_sizes[0] / 128;
  int N1 = in_sizes[1] / 128;
  int E = in_sizes[2];
  int nsrc[3] = {N0, N1, N0};
  int ndst[3] = {N1, N0, N0};
  int maxN = N0 > N1 ? N0 : N1;

  char* base = (char*)d_ws;
  size_t off = 0;
  auto alloc = [&](size_t bytes) -> void* {
    void* p = base + off;
    off += (bytes + 255) & ~(size_t)255;
    return p;
  };

  unsigned short* qb0 = (unsigned short*)alloc((size_t)N0 * 128 * 2);
  unsigned short* qb1 = (unsigned short*)alloc((size_t)N1 * 128 * 2);
  unsigned short* kvb[3];  // interleaved [N][kr(128) | vr(128)] bf16
  for (int r = 0; r < 3; ++r) kvb[r] = (unsigned short*)alloc((size_t)nsrc[r] * 256 * 2);
  unsigned short* Tb0 = (unsigned short*)alloc((size_t)N0 * 128 * 2);
  unsigned short* Tb1 = (unsigned short*)alloc((size_t)N1 * 128 * 2);
  unsigned short* Wkrb = (unsigned short*)alloc((size_t)3 * 16384 * 2);
  unsigned short* Wvrb = (unsigned short*)alloc((size_t)3 * 16384 * 2);
  unsigned short* Wqb = (unsigned short*)alloc((size_t)2 * 16384 * 2);
  unsigned short* Wab = (unsigned short*)alloc((size_t)2 * 16384 * 2);
  float* bkr = (float*)alloc(3 * 128 * 4);
  float* bvr = (float*)alloc(3 * 128 * 4);
  int* rp[3];
  int2* sd[3];
  unsigned short* eb[3];
  for (int r = 0; r < 3; ++r) {
    rp[r] = (int*)alloc((size_t)(ndst[r] + 1) * 4);
    sd[r] = (int2*)alloc((size_t)(E + 8) * 8);
    eb[r] = (unsigned short*)alloc((size_t)E * 8 * 2);
  }
  int* cnt6 = (int*)alloc((size_t)6 * maxN * 4);  // cnt (hist) + cur (scatter)
  int* bsum = (int*)alloc(3 * 256 * 4);
  (void)ws_size;

  // 1. weight prep
  compose_w_kernel<<<dim3(3, 128, 2), 128, 0, stream>>>(Wk, bk, Wv, bv, rel_att, rel_msg,
                                                        rel_pri, Wkrb, bkr, Wvrb, bvr);
  cvt2_kernel<<<dim3(16, 2), 256, 0, stream>>>(Wq, Wqb, Wa, Wab, 4096);

  // 2. fused projection GEMMs -> bf16 q + interleaved kv tables
  ProjFP pf;
  pf.A[0] = h0; pf.A[1] = h1;
  pf.M[0] = N0; pf.M[1] = N1;
  pf.nj[0] = 5; pf.nj[1] = 3;
  // type0 jobs: q, kr(rel0), kr(rel2), vr(rel0), vr(rel2)
  pf.W[0] = Wqb;            pf.b[0] = bq;        pf.out[0] = qb0;          pf.ostr[0] = 128;
  pf.W[1] = Wkrb;           pf.b[1] = bkr;       pf.out[1] = kvb[0];       pf.ostr[1] = 256;
  pf.W[2] = Wkrb + 32768;   pf.b[2] = bkr + 256; pf.out[2] = kvb[2];       pf.ostr[2] = 256;
  pf.W[3] = Wvrb;           pf.b[3] = bvr;       pf.out[3] = kvb[0] + 128; pf.ostr[3] = 256;
  pf.W[4] = Wvrb + 32768;   pf.b[4] = bvr + 256; pf.out[4] = kvb[2] + 128; pf.ostr[4] = 256;
  // type1 jobs: q, kr(rel1), vr(rel1)
  pf.W[5] = Wqb + 16384;    pf.b[5] = bq + 128;  pf.out[5] = qb1;          pf.ostr[5] = 128;
  pf.W[6] = Wkrb + 16384;   pf.b[6] = bkr + 128; pf.out[6] = kvb[1];       pf.ostr[6] = 256;
  pf.W[7] = Wvrb + 16384;   pf.b[7] = bvr + 128; pf.out[7] = kvb[1] + 128; pf.ostr[7] = 256;
  pf.W[8] = Wqb; pf.b[8] = bq; pf.out[8] = qb0; pf.ostr[8] = 128;  // unused
  pf.W[9] = Wqb; pf.b[9] = bq; pf.out[9] = qb0; pf.ostr[9] = 128;  // unused
  proj_gemm_fused<<<dim3((maxN + 127) / 128, 2), 256, 0, stream>>>(pf);

  // 3. CSR per relation (batched, gridDim.y = 3)
  hipMemsetAsync(cnt6, 0, (size_t)6 * maxN * 4, stream);
  hist3_kernel<<<dim3((E + 255) / 256, 3), 256, 0, stream>>>(dsts[0], dsts[1], dsts[2], cnt6,
                                                             maxN, E);
  int nb = (maxN + 1023) / 1024;
  scan1_kernel<<<dim3(nb, 3), 256, 0, stream>>>(cnt6, rp[0], rp[1], rp[2], bsum, maxN,
                                                ndst[0], ndst[1], ndst[2]);
  scan23_kernel<<<dim3((maxN + 255) / 256, 3), 256, 0, stream>>>(
      rp[0], rp[1], rp[2], bsum, nb, ndst[0], ndst[1], ndst[2], E);
  scatter3_kernel<<<dim3((E + 255) / 256, 3), 256, 0, stream>>>(
      srcs[0], dsts[0], srcs[1], dsts[1], srcs[2], dsts[2], rp[0], rp[1], rp[2],
      cnt6 + (size_t)3 * maxN, maxN, sd[0], sd[1], sd[2], E);

  // 4a. edge-parallel scores
  ScP sp;
  for (int r = 0; r < 3; ++r) {
    sp.sd[r] = sd[r];
    sp.kv[r] = (const unsigned*)kvb[r];
    sp.eb[r] = eb[r];
  }
  sp.qb[0] = (const unsigned*)qb1;  // rel0 dst type 1
  sp.qb[1] = (const unsigned*)qb0;  // rel1 dst type 0
  sp.qb[2] = (const unsigned*)qb0;  // rel2 dst type 0
  sp.E = E;
  score_kernel<<<dim3((E + 31) / 32, 3), 256, 0, stream>>>(sp);

  // 4b. light aggregation -> bf16 T
  AgP ap;
  ap.sd0 = sd[0]; ap.sd1 = sd[1]; ap.sd2 = sd[2];
  ap.eb0 = eb[0]; ap.eb1 = eb[1]; ap.eb2 = eb[2];
  ap.kv0 = (const unsigned*)kvb[0]; ap.kv1 = (const unsigned*)kvb[1];
  ap.kv2 = (const unsigned*)kvb[2];
  ap.rp0 = rp[0]; ap.rp1 = rp[1]; ap.rp2 = rp[2];
  ap.Tb0 = (unsigned*)Tb0; ap.Tb1 = (unsigned*)Tb1;
  ap.N0 = N0; ap.N1 = N1;
  int totw = N0 + N1;
  agg2_kernel<<<(totw + 3) / 4, 256, 0, stream>>>(ap);

  // 5. final GEMM + skip blend -> fp32 d_out
  final_gemm_mfma<<<dim3((maxN + 127) / 128, 2), 256, 0, stream>>>(
      (float*)d_out, Tb0, Tb1, Wab, ba, h0, h1, skip, N0, N1);
}